// Round 6
// baseline (656.625 us; speedup 1.0000x reference)
//
#include <hip/hip_runtime.h>
#include <hip/hip_bf16.h>

typedef __attribute__((ext_vector_type(4))) float f32x4;
typedef __attribute__((ext_vector_type(8))) short bf16x8;
typedef __attribute__((ext_vector_type(8))) unsigned short u16x8;

__device__ __forceinline__ unsigned short f2bf(float f) {
  unsigned int u = __builtin_bit_cast(unsigned int, f);
  unsigned int r = (u + 0x7FFFu + ((u >> 16) & 1u)) >> 16;
  return (unsigned short)r;
}
__device__ __forceinline__ float bf2f(unsigned short h) {
  unsigned int u = ((unsigned int)h) << 16;
  return __builtin_bit_cast(float, u);
}

__device__ __forceinline__ void gload_lds16(const void* g, void* l) {
  __builtin_amdgcn_global_load_lds(
      (__attribute__((address_space(1))) unsigned int*)g,
      (__attribute__((address_space(3))) unsigned int*)l, 16, 0, 0);
}

// ---------- fp32 -> bf16 bulk convert ----------
__global__ __launch_bounds__(256) void cvt_bf16(const float* __restrict__ in,
                                                unsigned short* __restrict__ out,
                                                long n) {
  long i = ((long)blockIdx.x * 256 + threadIdx.x) * 8;
  if (i >= n) return;
  f32x4 a = *(const f32x4*)(in + i);
  f32x4 b = *(const f32x4*)(in + i + 4);
  u16x8 o;
#pragma unroll
  for (int j = 0; j < 4; ++j) o[j] = f2bf(a[j]);
#pragma unroll
  for (int j = 0; j < 4; ++j) o[4 + j] = f2bf(b[j]);
  *(u16x8*)(out + i) = o;
}

// ---------- weight transpose + hi/lo split ----------
__global__ __launch_bounds__(256) void transpose_split(
    const float* __restrict__ W, unsigned short* __restrict__ Th,
    unsigned short* __restrict__ Tl, int K, int N) {
  __shared__ float tile[32][33];
  int n0 = blockIdx.x * 32, k0 = blockIdx.y * 32;
  int tx = threadIdx.x, ty = threadIdx.y;  // (32, 8)
#pragma unroll
  for (int r = 0; r < 4; ++r)
    tile[ty + 8 * r][tx] = W[(size_t)(k0 + ty + 8 * r) * N + n0 + tx];
  __syncthreads();
#pragma unroll
  for (int r = 0; r < 4; ++r) {
    float f = tile[tx][ty + 8 * r];
    unsigned short hi = f2bf(f);
    unsigned short lo = f2bf(f - bf2f(hi));
    size_t o = (size_t)(n0 + ty + 8 * r) * K + k0 + tx;
    Th[o] = hi;
    Tl[o] = lo;
  }
}

// ---------- bf16x2 GEMM ----------
// EPI: 0 = fp32 C; 1 = fp32 split-K partial (KSL slices); 2 = kv scatter
#define BM 128
#define BN 128
#define BK 64

template <int EPI, int KSL>
__global__ __launch_bounds__(256) void gemm2(
    const unsigned short* __restrict__ A, const unsigned short* __restrict__ Bh,
    const unsigned short* __restrict__ Bl, void* __restrict__ Cv,
    void* __restrict__ Cv2, int M, int N, int K) {
  __shared__ unsigned short Ald[BM * BK];
  __shared__ unsigned short Bhld[BN * BK];
  __shared__ unsigned short Blld[BN * BK];
  int tid = threadIdx.x, lane = tid & 63, wid = tid >> 6;
  int wr = wid >> 1, wc = wid & 1;
  // bijective XCD swizzle (nwg % 8 == 0 for all uses)
  int nwg = gridDim.x;
  int w = (blockIdx.x & 7) * (nwg >> 3) + (blockIdx.x >> 3);
  int nTN = N / BN;
  int bm, bn, ks;
  if constexpr (KSL == 1) {
    bm = w / nTN;
    bn = w % nTN;
    ks = 0;
  } else {
    bm = w / (nTN * KSL);
    int r = w % (nTN * KSL);
    bn = r / KSL;
    ks = r % KSL;
  }
  int kbeg = ks * (K / KSL), kend = kbeg + K / KSL;
  const unsigned short* Ab = A + (size_t)(bm * BM) * K;
  const unsigned short* Bhb = Bh + (size_t)(bn * BN) * K;
  const unsigned short* Blb = Bl + (size_t)(bn * BN) * K;
  int fr = lane & 15, fq = lane >> 4;
  int srow = lane >> 3, scol = (lane & 7) * 8;

  f32x4 acc[4][4];
#pragma unroll
  for (int i = 0; i < 4; ++i)
#pragma unroll
    for (int j = 0; j < 4; ++j) acc[i][j] = (f32x4){0.f, 0.f, 0.f, 0.f};

  for (int k0 = kbeg; k0 < kend; k0 += BK) {
#pragma unroll
    for (int i = 0; i < 4; ++i) {
      int c = wid * 4 + i;
      size_t go = (size_t)(c * 8 + srow) * K + k0 + scol;
      gload_lds16(Ab + go, &Ald[c * 512]);
      gload_lds16(Bhb + go, &Bhld[c * 512]);
      gload_lds16(Blb + go, &Blld[c * 512]);
    }
    __syncthreads();
#pragma unroll
    for (int kk = 0; kk < 2; ++kk) {
      bf16x8 af[4], bhf[4], blf[4];
#pragma unroll
      for (int i = 0; i < 4; ++i) {
        af[i] = *(const bf16x8*)&Ald[(wr * 64 + i * 16 + fr) * BK + kk * 32 + fq * 8];
        bhf[i] = *(const bf16x8*)&Bhld[(wc * 64 + i * 16 + fr) * BK + kk * 32 + fq * 8];
        blf[i] = *(const bf16x8*)&Blld[(wc * 64 + i * 16 + fr) * BK + kk * 32 + fq * 8];
      }
#pragma unroll
      for (int mi = 0; mi < 4; ++mi)
#pragma unroll
        for (int ni = 0; ni < 4; ++ni) {
          acc[mi][ni] = __builtin_amdgcn_mfma_f32_16x16x32_bf16(
              af[mi], bhf[ni], acc[mi][ni], 0, 0, 0);
          acc[mi][ni] = __builtin_amdgcn_mfma_f32_16x16x32_bf16(
              af[mi], blf[ni], acc[mi][ni], 0, 0, 0);
        }
    }
    __syncthreads();
  }

#pragma unroll
  for (int mi = 0; mi < 4; ++mi)
#pragma unroll
    for (int ni = 0; ni < 4; ++ni)
#pragma unroll
      for (int r = 0; r < 4; ++r) {
        int row = bm * BM + wr * 64 + mi * 16 + fq * 4 + r;
        int col = bn * BN + wc * 64 + ni * 16 + fr;
        if constexpr (EPI == 0) {
          ((float*)Cv)[(size_t)row * N + col] = acc[mi][ni][r];
        } else if constexpr (EPI == 1) {
          ((float*)Cv)[(size_t)ks * M * N + (size_t)row * N + col] =
              acc[mi][ni][r];
        } else {  // kv scatter
          if (col < 512) {
            int bt = row >> 6, key = row & 63, h = col >> 6, d = col & 63;
            ((float*)Cv)[(size_t)(bt * 8 + h) * 4096 + d * 64 + key] =
                acc[mi][ni][r];
          } else {
            ((float*)Cv2)[(size_t)row * 512 + (col - 512)] = acc[mi][ni][r];
          }
        }
      }
}

// ---------- gather rows by (b, t) ----------
__global__ __launch_bounds__(256) void gather_rows(const int* __restrict__ mask,
                                                   int* __restrict__ cnt,
                                                   int* __restrict__ idx) {
  int g = blockIdx.x * 256 + threadIdx.x;  // 0..8191
  int m = mask[g];
  if (m > 0) {
    int bt = (g >> 11) * 3 + m - 1;
    int p = atomicAdd(&cnt[bt], 1);
    idx[bt * 2048 + p] = g;
  }
}

// ---------- attention: block = (bucket, head, 64-row chunk) ----------
// K in regs (lane=key), one head's V in LDS; ~770 active blocks -> real TLP.
// q0/q1: [8192,512] fp32 split-K partials (q = q0+q1)
// kvT: [12][8][64d][64key] fp32; kvV: [768,512] fp32 (row=bt*64+key, col=h*64+d)
// attn: [8192,512] bf16 (pre-zeroed for masked rows)
__global__ __launch_bounds__(256) void attn4(
    const float* __restrict__ q0, const float* __restrict__ q1,
    const float* __restrict__ kvT, const float* __restrict__ kvV,
    const int* __restrict__ cnt, const int* __restrict__ idx,
    unsigned short* __restrict__ attn) {
  __shared__ float Vlds[64][64];  // [key][d] — PV reads lane=d, conflict-free
  __shared__ float pls[4][64];
  int tid = threadIdx.x, wid = tid >> 6, lane = tid & 63;
  int bt = blockIdx.x >> 8;          // /256
  int rem = blockIdx.x & 255;
  int h = rem >> 5, chunk = rem & 31;
  int n = cnt[bt];
  int base = chunk * 64;
  if (base >= n) return;
  int hi_end = min(base + 64, n);
  const int* list = idx + bt * 2048;

  // stage V[key][d] for this head (block-wide, 16 floats/thread)
  {
    int skey = tid >> 2, sdg = (tid & 3) * 16;
    const float* vsrc = kvV + (size_t)(bt * 64 + skey) * 512 + h * 64 + sdg;
#pragma unroll
    for (int i = 0; i < 4; ++i)
      *(f32x4*)&Vlds[skey][sdg + i * 4] = *(const f32x4*)(vsrc + i * 4);
  }
  // K row for this head: lane = key, kr[d]
  float kr[64];
  {
    const float* kt = kvT + (size_t)(bt * 8 + h) * 4096 + lane;
#pragma unroll
    for (int d = 0; d < 64; ++d) kr[d] = kt[d * 64];
  }
  __syncthreads();

  for (int j = base + wid; j < hi_end; j += 4) {
    int g = list[j];
    size_t qoff = (size_t)g * 512 + h * 64;
    float dot = 0.f;
#pragma unroll
    for (int c = 0; c < 16; ++c) {
      f32x4 qa = *(const f32x4*)(q0 + qoff + c * 4);  // broadcast loads
      f32x4 qb = *(const f32x4*)(q1 + qoff + c * 4);
      dot += (qa[0] + qb[0]) * kr[c * 4] + (qa[1] + qb[1]) * kr[c * 4 + 1] +
             (qa[2] + qb[2]) * kr[c * 4 + 2] + (qa[3] + qb[3]) * kr[c * 4 + 3];
    }
    float mx = dot;
#pragma unroll
    for (int o = 32; o; o >>= 1) mx = fmaxf(mx, __shfl_xor(mx, o));
    float p = __expf(dot - mx);
    float sm = p;
#pragma unroll
    for (int o = 32; o; o >>= 1) sm += __shfl_xor(sm, o);
    p /= sm;
    pls[wid][lane] = p;
    float acc = 0.f;
#pragma unroll
    for (int jj = 0; jj < 64; jj += 4) {
      f32x4 p4 = *(const f32x4*)&pls[wid][jj];  // broadcast read (free)
      acc += p4[0] * Vlds[jj][lane] + p4[1] * Vlds[jj + 1][lane] +
             p4[2] * Vlds[jj + 2][lane] + p4[3] * Vlds[jj + 3][lane];
    }
    attn[(size_t)g * 512 + h * 64 + lane] = f2bf(acc);
  }
}

// ---------- launch ----------
extern "C" void kernel_launch(void* const* d_in, const int* in_sizes, int n_in,
                              void* d_out, int out_size, void* d_ws,
                              size_t ws_size, hipStream_t stream) {
  const float* latent = (const float*)d_in[0];
  const float* y = (const float*)d_in[1];
  const int* mask = (const int*)d_in[2];
  const float* W_vk = (const float*)d_in[3];
  const float* W_q = (const float*)d_in[4];
  const float* W_out = (const float*)d_in[5];
  float* out = (float*)d_out;

  char* ws = (char*)d_ws;
  size_t off = 0;
  auto alloc = [&](size_t bytes) -> void* {
    void* p = ws + off;
    off = (off + bytes + 255) & ~(size_t)255;
    return p;
  };
  unsigned short* WqT_h = (unsigned short*)alloc((size_t)512 * 4096 * 2);
  unsigned short* WqT_l = (unsigned short*)alloc((size_t)512 * 4096 * 2);
  unsigned short* WvkT_h = (unsigned short*)alloc((size_t)1024 * 2048 * 2);
  unsigned short* WvkT_l = (unsigned short*)alloc((size_t)1024 * 2048 * 2);
  unsigned short* WoT_h = (unsigned short*)alloc((size_t)4096 * 512 * 2);
  unsigned short* WoT_l = (unsigned short*)alloc((size_t)4096 * 512 * 2);
  unsigned short* ybf = (unsigned short*)alloc((size_t)8192 * 4096 * 2);
  unsigned short* latbf = (unsigned short*)alloc((size_t)768 * 2048 * 2);
  float* qbuf = (float*)alloc((size_t)2 * 8192 * 512 * 4);  // split-K partials
  float* kvT = (float*)alloc((size_t)12 * 8 * 64 * 64 * 4);
  float* kvV = (float*)alloc((size_t)768 * 512 * 4);
  unsigned short* attnbuf = (unsigned short*)alloc((size_t)8192 * 512 * 2);
  int* cnt = (int*)alloc(12 * 4);
  int* idx = (int*)alloc((size_t)12 * 2048 * 4);

  hipMemsetAsync(cnt, 0, 12 * 4, stream);
  hipMemsetAsync(attnbuf, 0, (size_t)8192 * 512 * 2, stream);

  cvt_bf16<<<16384, 256, 0, stream>>>(y, ybf, (long)8192 * 4096);
  cvt_bf16<<<768, 256, 0, stream>>>(latent, latbf, (long)768 * 2048);

  dim3 tb(32, 8);
  transpose_split<<<dim3(16, 128), tb, 0, stream>>>(W_q, WqT_h, WqT_l, 4096, 512);
  transpose_split<<<dim3(32, 64), tb, 0, stream>>>(W_vk, WvkT_h, WvkT_l, 2048, 1024);
  transpose_split<<<dim3(128, 16), tb, 0, stream>>>(W_out, WoT_h, WoT_l, 512, 4096);

  gather_rows<<<32, 256, 0, stream>>>(mask, cnt, idx);

  // kv = latent[768,2048] @ W_vk ; scatter K -> kvT, V -> kvV
  gemm2<2, 1><<<(768 / BM) * (1024 / BN), 256, 0, stream>>>(
      latbf, WvkT_h, WvkT_l, kvT, kvV, 768, 1024, 2048);
  // q = y[8192,4096] @ W_q -> fp32 split-K partials (2 slices)
  gemm2<1, 2><<<(8192 / BM) * (512 / BN) * 2, 256, 0, stream>>>(
      ybf, WqT_h, WqT_l, qbuf, nullptr, 8192, 512, 4096);
  // attention: block = (bucket, head, 64-row chunk)
  attn4<<<12 * 8 * 32, 256, 0, stream>>>(qbuf, qbuf + (size_t)8192 * 512, kvT,
                                         kvV, cnt, idx, attnbuf);
  // out = attn[8192,512] @ W_out -> fp32
  gemm2<0, 1><<<(8192 / BM) * (4096 / BN), 256, 0, stream>>>(
      attnbuf, WoT_h, WoT_l, out, nullptr, 8192, 4096, 512);
}

// Round 7
// 352.099 us; speedup vs baseline: 1.8649x; 1.8649x over previous
//
#include <hip/hip_runtime.h>
#include <hip/hip_bf16.h>

typedef __attribute__((ext_vector_type(4))) float f32x4;
typedef __attribute__((ext_vector_type(8))) short bf16x8;
typedef __attribute__((ext_vector_type(8))) unsigned short u16x8;

__device__ __forceinline__ unsigned short f2bf(float f) {
  unsigned int u = __builtin_bit_cast(unsigned int, f);
  unsigned int r = (u + 0x7FFFu + ((u >> 16) & 1u)) >> 16;
  return (unsigned short)r;
}
__device__ __forceinline__ float bf2f(unsigned short h) {
  unsigned int u = ((unsigned int)h) << 16;
  return __builtin_bit_cast(float, u);
}

__device__ __forceinline__ void gload_lds16(const void* g, void* l) {
  __builtin_amdgcn_global_load_lds(
      (__attribute__((address_space(1))) unsigned int*)g,
      (__attribute__((address_space(3))) unsigned int*)l, 16, 0, 0);
}

// ---------- fp32 -> bf16 bulk convert ----------
__global__ __launch_bounds__(256) void cvt_bf16(const float* __restrict__ in,
                                                unsigned short* __restrict__ out,
                                                long n) {
  long i = ((long)blockIdx.x * 256 + threadIdx.x) * 8;
  if (i >= n) return;
  f32x4 a = *(const f32x4*)(in + i);
  f32x4 b = *(const f32x4*)(in + i + 4);
  u16x8 o;
#pragma unroll
  for (int j = 0; j < 4; ++j) o[j] = f2bf(a[j]);
#pragma unroll
  for (int j = 0; j < 4; ++j) o[4 + j] = f2bf(b[j]);
  *(u16x8*)(out + i) = o;
}

// ---------- weight transpose + hi/lo split ----------
__global__ __launch_bounds__(256) void transpose_split(
    const float* __restrict__ W, unsigned short* __restrict__ Th,
    unsigned short* __restrict__ Tl, int K, int N) {
  __shared__ float tile[32][33];
  int n0 = blockIdx.x * 32, k0 = blockIdx.y * 32;
  int tx = threadIdx.x, ty = threadIdx.y;  // (32, 8)
#pragma unroll
  for (int r = 0; r < 4; ++r)
    tile[ty + 8 * r][tx] = W[(size_t)(k0 + ty + 8 * r) * N + n0 + tx];
  __syncthreads();
#pragma unroll
  for (int r = 0; r < 4; ++r) {
    float f = tile[tx][ty + 8 * r];
    unsigned short hi = f2bf(f);
    unsigned short lo = f2bf(f - bf2f(hi));
    size_t o = (size_t)(n0 + ty + 8 * r) * K + k0 + tx;
    Th[o] = hi;
    Tl[o] = lo;
  }
}

// ---------- bf16x2 GEMM ----------
// EPI: 0 = fp32 C; 1 = fp32 split-K partial (KSL slices);
// EPI 2 = kv epilogue: K-half -> Kh/Kl bf16 [bt][h][key][d],
//                      V-half -> Vt bf16 [bt][h][d][key]
#define BM 128
#define BN 128
#define BK 64

template <int EPI, int KSL>
__global__ __launch_bounds__(256) void gemm2(
    const unsigned short* __restrict__ A, const unsigned short* __restrict__ Bh,
    const unsigned short* __restrict__ Bl, void* __restrict__ Cv,
    void* __restrict__ Cv2, void* __restrict__ Cv3, int M, int N, int K) {
  __shared__ unsigned short Ald[BM * BK];
  __shared__ unsigned short Bhld[BN * BK];
  __shared__ unsigned short Blld[BN * BK];
  int tid = threadIdx.x, lane = tid & 63, wid = tid >> 6;
  int wr = wid >> 1, wc = wid & 1;
  // bijective XCD swizzle (nwg % 8 == 0 for all uses)
  int nwg = gridDim.x;
  int w = (blockIdx.x & 7) * (nwg >> 3) + (blockIdx.x >> 3);
  int nTN = N / BN;
  int bm, bn, ks;
  if constexpr (KSL == 1) {
    bm = w / nTN;
    bn = w % nTN;
    ks = 0;
  } else {
    bm = w / (nTN * KSL);
    int r = w % (nTN * KSL);
    bn = r / KSL;
    ks = r % KSL;
  }
  int kbeg = ks * (K / KSL), kend = kbeg + K / KSL;
  const unsigned short* Ab = A + (size_t)(bm * BM) * K;
  const unsigned short* Bhb = Bh + (size_t)(bn * BN) * K;
  const unsigned short* Blb = Bl + (size_t)(bn * BN) * K;
  int fr = lane & 15, fq = lane >> 4;
  int srow = lane >> 3, scol = (lane & 7) * 8;

  f32x4 acc[4][4];
#pragma unroll
  for (int i = 0; i < 4; ++i)
#pragma unroll
    for (int j = 0; j < 4; ++j) acc[i][j] = (f32x4){0.f, 0.f, 0.f, 0.f};

  for (int k0 = kbeg; k0 < kend; k0 += BK) {
#pragma unroll
    for (int i = 0; i < 4; ++i) {
      int c = wid * 4 + i;
      size_t go = (size_t)(c * 8 + srow) * K + k0 + scol;
      gload_lds16(Ab + go, &Ald[c * 512]);
      gload_lds16(Bhb + go, &Bhld[c * 512]);
      gload_lds16(Blb + go, &Blld[c * 512]);
    }
    __syncthreads();
#pragma unroll
    for (int kk = 0; kk < 2; ++kk) {
      bf16x8 af[4], bhf[4], blf[4];
#pragma unroll
      for (int i = 0; i < 4; ++i) {
        af[i] = *(const bf16x8*)&Ald[(wr * 64 + i * 16 + fr) * BK + kk * 32 + fq * 8];
        bhf[i] = *(const bf16x8*)&Bhld[(wc * 64 + i * 16 + fr) * BK + kk * 32 + fq * 8];
        blf[i] = *(const bf16x8*)&Blld[(wc * 64 + i * 16 + fr) * BK + kk * 32 + fq * 8];
      }
#pragma unroll
      for (int mi = 0; mi < 4; ++mi)
#pragma unroll
        for (int ni = 0; ni < 4; ++ni) {
          acc[mi][ni] = __builtin_amdgcn_mfma_f32_16x16x32_bf16(
              af[mi], bhf[ni], acc[mi][ni], 0, 0, 0);
          acc[mi][ni] = __builtin_amdgcn_mfma_f32_16x16x32_bf16(
              af[mi], blf[ni], acc[mi][ni], 0, 0, 0);
        }
    }
    __syncthreads();
  }

#pragma unroll
  for (int mi = 0; mi < 4; ++mi)
#pragma unroll
    for (int ni = 0; ni < 4; ++ni)
#pragma unroll
      for (int r = 0; r < 4; ++r) {
        int row = bm * BM + wr * 64 + mi * 16 + fq * 4 + r;
        int col = bn * BN + wc * 64 + ni * 16 + fr;
        if constexpr (EPI == 0) {
          ((float*)Cv)[(size_t)row * N + col] = acc[mi][ni][r];
        } else if constexpr (EPI == 1) {
          ((float*)Cv)[(size_t)ks * M * N + (size_t)row * N + col] =
              acc[mi][ni][r];
        } else {  // kv epilogue
          int bt = row >> 6, key = row & 63;
          float v = acc[mi][ni][r];
          if (col < 512) {
            int h = col >> 6, d = col & 63;
            unsigned short hi = f2bf(v);
            unsigned short lo = f2bf(v - bf2f(hi));
            size_t o = ((size_t)(bt * 8 + h) * 64 + key) * 64 + d;
            ((unsigned short*)Cv)[o] = hi;   // Kh
            ((unsigned short*)Cv2)[o] = lo;  // Kl
          } else {
            int c = col - 512;
            int h = c >> 6, d = c & 63;
            ((unsigned short*)Cv3)[((size_t)(bt * 8 + h) * 64 + d) * 64 + key] =
                f2bf(v);  // Vt
          }
        }
      }
}

// ---------- gather rows by (b, t) ----------
__global__ __launch_bounds__(256) void gather_rows(const int* __restrict__ mask,
                                                   int* __restrict__ cnt,
                                                   int* __restrict__ idx) {
  int g = blockIdx.x * 256 + threadIdx.x;  // 0..8191
  int m = mask[g];
  if (m > 0) {
    int bt = (g >> 11) * 3 + m - 1;
    int p = atomicAdd(&cnt[bt], 1);
    idx[bt * 2048 + p] = g;
  }
}

// ---------- MFMA attention ----------
// block = (bucket bt, 32-row tile rt); 4 waves, wave handles heads 2w,2w+1.
// S = Q·K^T (M=32 rows, N=64 keys, K=64 d) with Q from fp32 split-K partials
// (hi/lo in-register, 3-term bf16x2), K from Kh/Kl. Softmax on fragments.
// O = P·Vt (K=64 keys). Output scattered to attnbuf rows (pre-zeroed).
__global__ __launch_bounds__(256) void attn5(
    const float* __restrict__ q0, const float* __restrict__ q1,
    const unsigned short* __restrict__ Kh, const unsigned short* __restrict__ Kl,
    const unsigned short* __restrict__ Vt, const int* __restrict__ cnt,
    const int* __restrict__ idx, unsigned short* __restrict__ attn) {
  __shared__ unsigned short Pl[4][32][72];  // padded: bank-friendly b128 reads
  __shared__ int glist[32];
  int tid = threadIdx.x, wid = tid >> 6, lane = tid & 63;
  int fr = lane & 15, fq = lane >> 4;
  int bt = blockIdx.x >> 6, rt = blockIdx.x & 63;
  int n = cnt[bt];
  int rbase = rt * 32;
  if (rbase >= n) return;
  const int* list = idx + bt * 2048;
  if (tid < 32) {
    int j = rbase + tid;
    glist[tid] = (j < n) ? list[j] : list[0];  // safe dummy for tail rows
  }
  __syncthreads();

#pragma unroll 1
  for (int hp = 0; hp < 2; ++hp) {
    int h = wid * 2 + hp;
    const unsigned short* khb = Kh + ((size_t)(bt * 8 + h) * 64) * 64;
    const unsigned short* klb = Kl + ((size_t)(bt * 8 + h) * 64) * 64;
    const unsigned short* vtb = Vt + ((size_t)(bt * 8 + h) * 64) * 64;

    f32x4 sacc[2][4];
#pragma unroll
    for (int i = 0; i < 2; ++i)
#pragma unroll
      for (int j = 0; j < 4; ++j) sacc[i][j] = (f32x4){0.f, 0.f, 0.f, 0.f};

#pragma unroll
    for (int kk = 0; kk < 2; ++kk) {
      // Q fragments: sum split-K partials, split hi/lo in-register
      bf16x8 qh[2], ql[2];
#pragma unroll
      for (int mi = 0; mi < 2; ++mi) {
        int g = glist[mi * 16 + fr];
        size_t qo = (size_t)g * 512 + h * 64 + kk * 32 + fq * 8;
        f32x4 a0 = *(const f32x4*)(q0 + qo);
        f32x4 a1 = *(const f32x4*)(q0 + qo + 4);
        f32x4 b0 = *(const f32x4*)(q1 + qo);
        f32x4 b1 = *(const f32x4*)(q1 + qo + 4);
        float sv[8];
        *(f32x4*)&sv[0] = a0 + b0;
        *(f32x4*)&sv[4] = a1 + b1;
#pragma unroll
        for (int j = 0; j < 8; ++j) {
          unsigned short hi = f2bf(sv[j]);
          qh[mi][j] = (short)hi;
          ql[mi][j] = (short)f2bf(sv[j] - bf2f(hi));
        }
      }
#pragma unroll
      for (int ni = 0; ni < 4; ++ni) {
        size_t ko = (size_t)(ni * 16 + fr) * 64 + kk * 32 + fq * 8;
        bf16x8 kh = *(const bf16x8*)(khb + ko);
        bf16x8 kl = *(const bf16x8*)(klb + ko);
#pragma unroll
        for (int mi = 0; mi < 2; ++mi) {
          sacc[mi][ni] = __builtin_amdgcn_mfma_f32_16x16x32_bf16(
              qh[mi], kh, sacc[mi][ni], 0, 0, 0);
          sacc[mi][ni] = __builtin_amdgcn_mfma_f32_16x16x32_bf16(
              qh[mi], kl, sacc[mi][ni], 0, 0, 0);
          sacc[mi][ni] = __builtin_amdgcn_mfma_f32_16x16x32_bf16(
              ql[mi], kh, sacc[mi][ni], 0, 0, 0);
        }
      }
    }

    // softmax over keys: lane holds rows {mi*16+fq*4+r}, cols {ni*16+fr}
#pragma unroll
    for (int mi = 0; mi < 2; ++mi) {
#pragma unroll
      for (int r = 0; r < 4; ++r) {
        float m = fmaxf(fmaxf(sacc[mi][0][r], sacc[mi][1][r]),
                        fmaxf(sacc[mi][2][r], sacc[mi][3][r]));
#pragma unroll
        for (int o = 1; o < 16; o <<= 1) m = fmaxf(m, __shfl_xor(m, o));
        float e0 = __expf(sacc[mi][0][r] - m);
        float e1 = __expf(sacc[mi][1][r] - m);
        float e2 = __expf(sacc[mi][2][r] - m);
        float e3 = __expf(sacc[mi][3][r] - m);
        float s = e0 + e1 + e2 + e3;
#pragma unroll
        for (int o = 1; o < 16; o <<= 1) s += __shfl_xor(s, o);
        float inv = 1.f / s;
        int row = mi * 16 + fq * 4 + r;
        Pl[wid][row][fr] = f2bf(e0 * inv);
        Pl[wid][row][16 + fr] = f2bf(e1 * inv);
        Pl[wid][row][32 + fr] = f2bf(e2 * inv);
        Pl[wid][row][48 + fr] = f2bf(e3 * inv);
      }
    }

    // O = P · Vt  (A = P [32 rows][64 keys], B = Vt [64 d][64 keys])
    f32x4 oacc[2][4];
#pragma unroll
    for (int i = 0; i < 2; ++i)
#pragma unroll
      for (int j = 0; j < 4; ++j) oacc[i][j] = (f32x4){0.f, 0.f, 0.f, 0.f};
#pragma unroll
    for (int kk = 0; kk < 2; ++kk) {
      bf16x8 pa[2];
#pragma unroll
      for (int mi = 0; mi < 2; ++mi)
        pa[mi] = *(const bf16x8*)&Pl[wid][mi * 16 + fr][kk * 32 + fq * 8];
#pragma unroll
      for (int ni = 0; ni < 4; ++ni) {
        bf16x8 vb = *(const bf16x8*)(vtb + (size_t)(ni * 16 + fr) * 64 +
                                     kk * 32 + fq * 8);
#pragma unroll
        for (int mi = 0; mi < 2; ++mi)
          oacc[mi][ni] = __builtin_amdgcn_mfma_f32_16x16x32_bf16(
              pa[mi], vb, oacc[mi][ni], 0, 0, 0);
      }
    }

    // scatter-store: row -> g = glist[row], col = h*64 + ni*16 + fr
#pragma unroll
    for (int mi = 0; mi < 2; ++mi)
#pragma unroll
      for (int r = 0; r < 4; ++r) {
        int row = mi * 16 + fq * 4 + r;
        if (rbase + row < n) {
          int g = glist[row];
          unsigned short* ar = attn + (size_t)g * 512 + h * 64 + fr;
          ar[0] = f2bf(oacc[mi][0][r]);
          ar[16] = f2bf(oacc[mi][1][r]);
          ar[32] = f2bf(oacc[mi][2][r]);
          ar[48] = f2bf(oacc[mi][3][r]);
        }
      }
  }
}

// ---------- launch ----------
extern "C" void kernel_launch(void* const* d_in, const int* in_sizes, int n_in,
                              void* d_out, int out_size, void* d_ws,
                              size_t ws_size, hipStream_t stream) {
  const float* latent = (const float*)d_in[0];
  const float* y = (const float*)d_in[1];
  const int* mask = (const int*)d_in[2];
  const float* W_vk = (const float*)d_in[3];
  const float* W_q = (const float*)d_in[4];
  const float* W_out = (const float*)d_in[5];
  float* out = (float*)d_out;

  char* ws = (char*)d_ws;
  size_t off = 0;
  auto alloc = [&](size_t bytes) -> void* {
    void* p = ws + off;
    off = (off + bytes + 255) & ~(size_t)255;
    return p;
  };
  unsigned short* WqT_h = (unsigned short*)alloc((size_t)512 * 4096 * 2);
  unsigned short* WqT_l = (unsigned short*)alloc((size_t)512 * 4096 * 2);
  unsigned short* WvkT_h = (unsigned short*)alloc((size_t)1024 * 2048 * 2);
  unsigned short* WvkT_l = (unsigned short*)alloc((size_t)1024 * 2048 * 2);
  unsigned short* WoT_h = (unsigned short*)alloc((size_t)4096 * 512 * 2);
  unsigned short* WoT_l = (unsigned short*)alloc((size_t)4096 * 512 * 2);
  unsigned short* ybf = (unsigned short*)alloc((size_t)8192 * 4096 * 2);
  unsigned short* latbf = (unsigned short*)alloc((size_t)768 * 2048 * 2);
  float* qbuf = (float*)alloc((size_t)2 * 8192 * 512 * 4);  // split-K partials
  unsigned short* Khb = (unsigned short*)alloc((size_t)768 * 512 * 2);
  unsigned short* Klb = (unsigned short*)alloc((size_t)768 * 512 * 2);
  unsigned short* Vtb = (unsigned short*)alloc((size_t)768 * 512 * 2);
  unsigned short* attnbuf = (unsigned short*)alloc((size_t)8192 * 512 * 2);
  int* cnt = (int*)alloc(12 * 4);
  int* idx = (int*)alloc((size_t)12 * 2048 * 4);

  hipMemsetAsync(cnt, 0, 12 * 4, stream);
  hipMemsetAsync(attnbuf, 0, (size_t)8192 * 512 * 2, stream);

  cvt_bf16<<<16384, 256, 0, stream>>>(y, ybf, (long)8192 * 4096);
  cvt_bf16<<<768, 256, 0, stream>>>(latent, latbf, (long)768 * 2048);

  dim3 tb(32, 8);
  transpose_split<<<dim3(16, 128), tb, 0, stream>>>(W_q, WqT_h, WqT_l, 4096, 512);
  transpose_split<<<dim3(32, 64), tb, 0, stream>>>(W_vk, WvkT_h, WvkT_l, 2048, 1024);
  transpose_split<<<dim3(128, 16), tb, 0, stream>>>(W_out, WoT_h, WoT_l, 512, 4096);

  gather_rows<<<32, 256, 0, stream>>>(mask, cnt, idx);

  // kv = latent[768,2048] @ W_vk ; epilogue -> Kh/Kl [bt][h][key][d], Vt [bt][h][d][key]
  gemm2<2, 1><<<(768 / BM) * (1024 / BN), 256, 0, stream>>>(
      latbf, WvkT_h, WvkT_l, Khb, Klb, Vtb, 768, 1024, 2048);
  // q = y[8192,4096] @ W_q -> fp32 split-K partials (2 slices)
  gemm2<1, 2><<<(8192 / BM) * (512 / BN) * 2, 256, 0, stream>>>(
      ybf, WqT_h, WqT_l, qbuf, nullptr, nullptr, 8192, 512, 4096);
  // MFMA attention
  attn5<<<12 * 64, 256, 0, stream>>>(qbuf, qbuf + (size_t)8192 * 512, Khb, Klb,
                                     Vtb, cnt, idx, attnbuf);
  // out = attn[8192,512] @ W_out -> fp32
  gemm2<0, 1><<<(8192 / BM) * (4096 / BN), 256, 0, stream>>>(
      attnbuf, WoT_h, WoT_l, out, nullptr, nullptr, 8192, 4096, 512);
}